// Round 10
// baseline (158.043 us; speedup 1.0000x reference)
//
#include <hip/hip_runtime.h>
#include <hip/hip_bf16.h>
#include <math.h>

#define HID 128
#define ATT 64
#define HOPS 8
#define T_ 64
#define N_ 64
#define B_ 64
#define L_ 4096

typedef __attribute__((ext_vector_type(8))) short bf16x8;
typedef __attribute__((ext_vector_type(4))) float f32x4;

static constexpr size_t OFF_A     = (size_t)B_ * N_ * T_;              // 262144
static constexpr size_t OFF_NEIGH = OFF_A + (size_t)B_ * HOPS * L_;    // 2359296
static constexpr size_t OFF_PENAL = OFF_NEIGH + (size_t)B_ * L_ * HID; // 35913728

#define NSTRIP 16384            // 64 batches * 256 strips (16 rows each)
#define NWAVE  6144             // 768 blocks * 8 waves

__device__ __forceinline__ unsigned pkbf(float lo, float hi) {
    unsigned a = (unsigned)(unsigned short)__builtin_bit_cast(unsigned short, __float2bfloat16(lo));
    unsigned b = (unsigned)(unsigned short)__builtin_bit_cast(unsigned short, __float2bfloat16(hi));
    return a | (b << 16);
}
__device__ __forceinline__ short f2bf(float x) {
    return __builtin_bit_cast(short, __float2bfloat16(x));
}
__device__ __forceinline__ float bflo(unsigned u) { return __builtin_bit_cast(float, u << 16); }
__device__ __forceinline__ float bfhi(unsigned u) { return __builtin_bit_cast(float, u & 0xffff0000u); }

// LDS-only barrier: waits own ds_writes, does NOT drain vmcnt.
__device__ __forceinline__ void lds_barrier() {
    asm volatile("s_waitcnt lgkmcnt(0)" ::: "memory");
    __builtin_amdgcn_s_barrier();
}

// ---------------- K0: W1 f32 -> bf16 in workspace (run once, tiny) ----------------
__global__ __launch_bounds__(256)
void k0_w1(const float* __restrict__ W1, unsigned* __restrict__ wsW1)
{
    const int t = threadIdx.x;               // 256 threads x 32 floats = 8192
    const float* src = W1 + t * 32;
    float x[32];
    #pragma unroll
    for (int i = 0; i < 8; ++i) *(float4*)&x[i * 4] = *(const float4*)(src + i * 4);
    unsigned u[16];
    #pragma unroll
    for (int i = 0; i < 16; ++i) u[i] = pkbf(x[2 * i], x[2 * i + 1]);
    #pragma unroll
    for (int i = 0; i < 4; ++i)
        *(uint4*)&wsW1[t * 16 + i * 4] = *(uint4*)&u[i * 4];
}

// ---------------- K1: per-wave strips, single-buffer, 24 waves/CU ----------------
// 768 blocks x 512 thr = 6144 waves; wave W handles strips W, W+6144, W+12288.
// Strip = 16 rows x 128 f32 (8 KB). Per load/store instr: 2 rows x 1KB contiguous.
// LDS 53 KB -> 3 blocks/CU; launch_bounds(512,6) -> VGPR cap 85 -> 24 waves/CU.
// th tile reuses the per-wave H region (safe: af reads precede th writes in-wave;
// af never reads the [64,68) row pad where th data survives the next hp rewrite).
__global__ __launch_bounds__(512, 6)
void k1_mfma(const float* __restrict__ node, const float* __restrict__ neigh,
             const int* __restrict__ nnum, const unsigned* __restrict__ wsW1,
             const float* __restrict__ b1, const float* __restrict__ W2,
             const float* __restrict__ b2, float* __restrict__ out)
{
    __shared__ __align__(16) unsigned w1lds[64 * 68];     // 17.0 KB  W1 bf16 pairs [a][kp]
    __shared__ __align__(16) uint4    w2lds[128];         //  2.0 KB  per-lane W2 B-frags
    __shared__ __align__(16) unsigned hlds [8 * 1088];    // 34.0 KB  per-wave H / th tiles

    const int tid  = threadIdx.x;
    const int w    = tid >> 6;
    const int lane = tid & 63;
    const int c    = lane & 15;
    const int g    = lane >> 4;
    const int ro   = lane >> 5;          // row parity within 2-row span
    const int p    = lane & 31;          // 16B piece within 1KB span

    const int W = blockIdx.x * 8 + w;    // global wave id, 0..6143

    // ---- prologue: strip-0 loads in flight across all staging ----
    int s = W;
    float4 v[8];
    uint2  npk[8];
    {
        const float* npb = neigh + (size_t)s * 2048;
        #pragma unroll
        for (int j = 0; j < 8; ++j)
            v[j] = *(const float4*)(npb + (2 * j + ro) * HID + p * 4);
        const float* nd = node + (size_t)(s >> 8) * 8192 + (size_t)(s & 3) * 2048;
        #pragma unroll
        for (int j = 0; j < 8; ++j) {
            float4 nv = *(const float4*)(nd + (2 * j + ro) * HID + p * 4);
            npk[j].x = pkbf(nv.x, nv.y);
            npk[j].y = pkbf(nv.z, nv.w);
        }
    }

    // ---- stage W1 bf16 ws -> LDS (512 thr x 32B) ----
    {
        const int row = tid >> 3, seg = tid & 7;
        const unsigned* srcu = wsW1 + row * 64 + seg * 8;
        uint4 a0 = *(const uint4*)(srcu);
        uint4 a1 = *(const uint4*)(srcu + 4);
        *(uint4*)&w1lds[row * 68 + seg * 8]     = a0;
        *(uint4*)&w1lds[row * 68 + seg * 8 + 4] = a1;
    }
    // ---- stage W2 B-fragments (128 thr) ----
    if (tid < 128) {
        const int ln = tid >> 1, ks2 = tid & 1;
        const int cc = ln & 15, gg = ln >> 4;
        unsigned u[4];
        #pragma unroll
        for (int i = 0; i < 4; ++i) {
            float lo = (cc < 8) ? W2[cc * 64 + ks2 * 32 + gg * 8 + 2 * i]     : 0.f;
            float hi = (cc < 8) ? W2[cc * 64 + ks2 * 32 + gg * 8 + 2 * i + 1] : 0.f;
            u[i] = pkbf(lo, hi);
        }
        uint4 t4; t4.x = u[0]; t4.y = u[1]; t4.z = u[2]; t4.w = u[3];
        w2lds[ln * 2 + ks2] = t4;
    }

    float b1v[4];
    #pragma unroll
    for (int cf = 0; cf < 4; ++cf) b1v[cf] = b1[cf * 16 + c];
    const float b2v = (c < 8) ? b2[c] : 0.f;
    const float inv_scale = rsqrtf((float)nnum[0]);

    lds_barrier();                       // publish W1/W2; v/npk loads survive

    unsigned*       hw  = &hlds[w * 1088];
    const unsigned* hr  = &hlds[w * 1088 + c * 68 + g * 4];
    const unsigned* w1p = &w1lds[c * 68 + g * 4];
    short*          thw = (short*)hw;

    #pragma unroll 1
    for (;;) {
        const size_t base = (size_t)s * 2048;
        float* cd = out + OFF_NEIGH + base;

        // ---- pack H (waits v progressively) + private-LDS write ----
        #pragma unroll
        for (int j = 0; j < 8; ++j) {
            uint2 hp;
            hp.x = pkbf(v[j].x * bflo(npk[j].x), v[j].y * bfhi(npk[j].x));
            hp.y = pkbf(v[j].z * bflo(npk[j].y), v[j].w * bfhi(npk[j].y));
            *(uint2*)&hw[(2 * j + ro) * 68 + 2 * p] = hp;
        }
        // ---- copy-out stores (v still live; full-line 1KB spans) ----
        #pragma unroll
        for (int j = 0; j < 8; ++j)
            *(float4*)(cd + (2 * j + ro) * HID + p * 4) = v[j];

        // ---- prefetch next strip into the SAME regs (v dead after stores) ----
        const int sn = s + NWAVE;
        const bool more = sn < NSTRIP;
        if (more) {
            const float* npb = neigh + (size_t)sn * 2048;
            #pragma unroll
            for (int j = 0; j < 8; ++j)
                v[j] = *(const float4*)(npb + (2 * j + ro) * HID + p * 4);
            const float* nd = node + (size_t)(sn >> 8) * 8192 + (size_t)(sn & 3) * 2048;
            #pragma unroll
            for (int j = 0; j < 8; ++j) {
                float4 nv = *(const float4*)(nd + (2 * j + ro) * HID + p * 4);
                npk[j].x = pkbf(nv.x, nv.y);
                npk[j].y = pkbf(nv.z, nv.w);
            }
        }

        // ---- s1 GEMM: A-frags from private LDS x W1 B-frags (16 MFMA) ----
        bf16x8 af[4];
        #pragma unroll
        for (int ks = 0; ks < 4; ++ks)
            af[ks] = *reinterpret_cast<const bf16x8*>(hr + ks * 16);
        f32x4 acc[4];
        #pragma unroll
        for (int cf = 0; cf < 4; ++cf) acc[cf] = (f32x4){0.f, 0.f, 0.f, 0.f};
        #pragma unroll
        for (int cf = 0; cf < 4; ++cf) {
            #pragma unroll
            for (int ks = 0; ks < 4; ++ks) {
                const bf16x8 wf = *reinterpret_cast<const bf16x8*>(w1p + cf * 1088 + ks * 16);
                acc[cf] = __builtin_amdgcn_mfma_f32_16x16x32_bf16(af[ks], wf, acc[cf], 0, 0, 0);
            }
        }
        // ---- tanh -> th tile (reuses hlds region; af already consumed) ----
        #pragma unroll
        for (int cf = 0; cf < 4; ++cf) {
            #pragma unroll
            for (int jj = 0; jj < 4; ++jj) {
                float th = (acc[cf][jj] + b1v[cf]) * inv_scale;
                th = 1.0f - 2.0f / (__expf(2.0f * th) + 1.0f);   // tanh, inf-safe
                thw[(g * 4 + jj) * 72 + cf * 16 + c] = f2bf(th);
            }
        }
        // ---- s2 MFMA + store ----
        f32x4 acc2 = (f32x4){0.f, 0.f, 0.f, 0.f};
        #pragma unroll
        for (int ks2 = 0; ks2 < 2; ++ks2) {
            bf16x8 pa = *reinterpret_cast<const bf16x8*>(&thw[c * 72 + ks2 * 32 + g * 8]);
            bf16x8 wf = *reinterpret_cast<const bf16x8*>(&w2lds[((g * 16 + c) & 63) * 2 + ks2]);
            acc2 = __builtin_amdgcn_mfma_f32_16x16x32_bf16(pa, wf, acc2, 0, 0, 0);
        }
        if (c < 8) {
            const int b = s >> 8, q = s & 255;
            float* s2b = out + OFF_A + (size_t)b * HOPS * L_;
            float4 o;
            o.x = acc2[0] + b2v; o.y = acc2[1] + b2v;
            o.z = acc2[2] + b2v; o.w = acc2[3] + b2v;
            *(float4*)&s2b[(size_t)c * L_ + q * 16 + g * 4] = o;
        }
        if (!more) break;
        s = sn;
    }
}

// ---------------- reductions helpers ----------------
__device__ __forceinline__ float waveMax(float v) {
    #pragma unroll
    for (int o = 32; o > 0; o >>= 1) v = fmaxf(v, __shfl_xor(v, o));
    return v;
}
__device__ __forceinline__ float waveSum(float v) {
    #pragma unroll
    for (int o = 32; o > 0; o >>= 1) v += __shfl_xor(v, o);
    return v;
}

// ---------------- K2: per-(b,h) softmax stats + zero aat accumulators ----------------
__global__ __launch_bounds__(256)
void k2_stats(const float* __restrict__ out, float* __restrict__ stats, float* __restrict__ aat)
{
    const int bh = blockIdx.x;                         // 0..511
    const int tid = threadIdx.x;
    if (bh == 0) {
        for (int i = tid; i < B_ * 36; i += 256) aat[i] = 0.f;
    }
    const float* row = out + OFF_A + (size_t)bh * L_;
    __shared__ float red[8];
    float m = -3.4e38f;
    for (int i = tid; i < L_; i += 256) m = fmaxf(m, row[i]);
    m = waveMax(m);
    if ((tid & 63) == 0) red[tid >> 6] = m;
    __syncthreads();
    const float M = fmaxf(fmaxf(red[0], red[1]), fmaxf(red[2], red[3]));
    float s = 0.0f;
    for (int i = tid; i < L_; i += 256) s += __expf(row[i] - M);
    s = waveSum(s);
    if ((tid & 63) == 0) red[4 + (tid >> 6)] = s;
    __syncthreads();
    if (tid == 0) {
        stats[bh * 2]     = M;
        stats[bh * 2 + 1] = red[4] + red[5] + red[6] + red[7];
    }
}

// ---------------- K3: in-place A = softmax, BW, AAT upper-tri partials (atomic) -------
__global__ __launch_bounds__(256)
void k3_soft(float* __restrict__ out, const float* __restrict__ stats, float* __restrict__ aat)
{
    const int blk = blockIdx.x;        // 256 blocks, 4 per batch
    const int b   = blk >> 2;
    const int l0  = (blk & 3) << 10;   // 1024 l's each
    const int tid = threadIdx.x;
    float* A0 = out + OFF_A + (size_t)b * HOPS * L_;
    float* BW = out + (size_t)b * L_;
    float M[HOPS], R[HOPS];
    #pragma unroll
    for (int hh = 0; hh < HOPS; ++hh) {
        M[hh] = stats[(b * HOPS + hh) * 2];
        R[hh] = 1.0f / stats[(b * HOPS + hh) * 2 + 1];
    }
    float p[36];
    #pragma unroll
    for (int i = 0; i < 36; ++i) p[i] = 0.0f;
    for (int l = l0 + tid; l < l0 + 1024; l += 256) {
        float e[HOPS]; float srow = 0.0f;
        #pragma unroll
        for (int hh = 0; hh < HOPS; ++hh) {
            float v = __expf(A0[hh * L_ + l] - M[hh]) * R[hh];
            e[hh] = v; srow += v;
        }
        #pragma unroll
        for (int hh = 0; hh < HOPS; ++hh) A0[hh * L_ + l] = e[hh];
        BW[l] = srow;
        int i = 0;
        #pragma unroll
        for (int hh = 0; hh < HOPS; ++hh) {
            #pragma unroll
            for (int gg = hh; gg < HOPS; ++gg) { p[i] = fmaf(e[hh], e[gg], p[i]); ++i; }
        }
    }
    #pragma unroll
    for (int i = 0; i < 36; ++i) p[i] = waveSum(p[i]);
    __shared__ float red[4][36];
    const int wv = tid >> 6, ln = tid & 63;
    if (ln == 0) {
        #pragma unroll
        for (int i = 0; i < 36; ++i) red[wv][i] = p[i];
    }
    __syncthreads();
    if (tid < 36) {
        float s = red[0][tid] + red[1][tid] + red[2][tid] + red[3][tid];
        atomicAdd(&aat[b * 36 + tid], s);
    }
}

// ---------------- K4: penal = sum_b sum((AAT_b - I)^2), off-diag counted twice --------
__global__ __launch_bounds__(256)
void k4_penal(const float* __restrict__ aat, float* __restrict__ out)
{
    const int tid = threadIdx.x;
    float s = 0.0f;
    for (int i = tid; i < B_ * 36; i += 256) {
        int r = i % 36;
        bool dg = (r == 0) | (r == 8) | (r == 15) | (r == 21) |
                  (r == 26) | (r == 30) | (r == 33) | (r == 35);
        float d = aat[i] - (dg ? 1.0f : 0.0f);
        float qd = d * d;
        s += dg ? qd : 2.0f * qd;
    }
    s = waveSum(s);
    __shared__ float red[4];
    if ((tid & 63) == 0) red[tid >> 6] = s;
    __syncthreads();
    if (tid == 0) out[OFF_PENAL] = red[0] + red[1] + red[2] + red[3];
}

extern "C" void kernel_launch(void* const* d_in, const int* in_sizes, int n_in,
                              void* d_out, int out_size, void* d_ws, size_t ws_size,
                              hipStream_t stream) {
    const float* node  = (const float*)d_in[0];
    const float* neigh = (const float*)d_in[1];
    const int*   nnum  = (const int*)d_in[2];   // low 32 bits of elem 0 (LE, value in [1,64))
    const float* W1    = (const float*)d_in[3];
    const float* b1    = (const float*)d_in[4];
    const float* W2    = (const float*)d_in[5];
    const float* b2    = (const float*)d_in[6];
    float* out   = (float*)d_out;
    float* stats = (float*)d_ws;                      // 1024 floats
    float* aat   = stats + 1024;                      // 64*36 floats
    unsigned* wsW1 = (unsigned*)d_ws + 4096;          // 16 KB (4096 u32) at 16KB offset

    k0_w1   <<<1, 256, 0, stream>>>(W1, wsW1);
    k1_mfma <<<768, 512, 0, stream>>>(node, neigh, nnum, wsW1, b1, W2, b2, out);
    k2_stats<<<B_ * HOPS, 256, 0, stream>>>(out, stats, aat);
    k3_soft <<<256, 256, 0, stream>>>(out, stats, aat);
    k4_penal<<<1, 256, 0, stream>>>(aat, out);
}

// Round 11
// 83.491 us; speedup vs baseline: 1.8929x; 1.8929x over previous
//
#include <hip/hip_runtime.h>
#include <hip/hip_bf16.h>
#include <math.h>

#define HID 128
#define ATT 64
#define HOPS 8
#define T_ 64
#define N_ 64
#define B_ 64
#define L_ 4096

typedef __attribute__((ext_vector_type(8))) short bf16x8;
typedef __attribute__((ext_vector_type(4))) float f32x4;

static constexpr size_t OFF_A     = (size_t)B_ * N_ * T_;              // 262144
static constexpr size_t OFF_NEIGH = OFF_A + (size_t)B_ * HOPS * L_;    // 2359296
static constexpr size_t OFF_PENAL = OFF_NEIGH + (size_t)B_ * L_ * HID; // 35913728

__device__ __forceinline__ unsigned pkbf(float lo, float hi) {
    unsigned a = (unsigned)(unsigned short)__builtin_bit_cast(unsigned short, __float2bfloat16(lo));
    unsigned b = (unsigned)(unsigned short)__builtin_bit_cast(unsigned short, __float2bfloat16(hi));
    return a | (b << 16);
}
__device__ __forceinline__ short f2bf(float x) {
    return __builtin_bit_cast(short, __float2bfloat16(x));
}
__device__ __forceinline__ float bflo(unsigned u) { return __builtin_bit_cast(float, u << 16); }
__device__ __forceinline__ float bfhi(unsigned u) { return __builtin_bit_cast(float, u & 0xffff0000u); }

// LDS-only barrier: waits own ds_writes, does NOT drain vmcnt -> prefetch loads
// and copy-out stores stay in flight across it (T3/T4 pattern).
__device__ __forceinline__ void lds_barrier() {
    asm volatile("s_waitcnt lgkmcnt(0)" ::: "memory");
    __builtin_amdgcn_s_barrier();
}

__device__ __forceinline__ void load_tile(float4 v[8], const float* nb, int tid) {
    #pragma unroll
    for (int r = 0; r < 8; ++r) v[r] = *(const float4*)(nb + r * 1024 + tid * 4);
}
__device__ __forceinline__ void store_tile(const float4 v[8], float* cb, int tid) {
    #pragma unroll
    for (int r = 0; r < 8; ++r) *(float4*)(cb + r * 1024 + tid * 4) = v[r];
}
// pack H = neigh*node (bf16 domain) into block-wide 64x68 tile
__device__ __forceinline__ void pack_tile(const float4 v[8], const uint2 npk[8],
                                          unsigned* hbuf, int tid) {
    const int arow0 = tid >> 5;
    const int acol  = (tid * 4) & 127;
    #pragma unroll
    for (int r = 0; r < 8; ++r) {
        const int row = r * 8 + arow0;
        uint2 pp;
        pp.x = pkbf(v[r].x * bflo(npk[r].x), v[r].y * bfhi(npk[r].x));
        pp.y = pkbf(v[r].z * bflo(npk[r].y), v[r].w * bfhi(npk[r].y));
        *(uint2*)&hbuf[row * 68 + (acol >> 1)] = pp;
    }
}

// compute: af from wave-private rows of hcur, 16 MFMA s1, tanh -> th ALIASED into
// hcur's wave region (safe: in-wave DS order puts af reads before th writes; other
// waves touch disjoint rows), 2 MFMA s2, store.
__device__ __forceinline__ void compute_tile(unsigned* hcur, const unsigned* w1l,
                                             const bf16x8 wf2[2], const float b1v[4],
                                             float b2v, float inv_scale,
                                             float* s2b, int tile, int w, int c, int g) {
    const unsigned* hr  = hcur + (w * 16 + c) * 68 + g * 4;
    const unsigned* w1p = w1l + c * 68 + g * 4;
    short* thw = (short*)(hcur + w * 1088);    // wave-private 16-row region reuse

    bf16x8 af[4];
    #pragma unroll
    for (int ks = 0; ks < 4; ++ks)
        af[ks] = *reinterpret_cast<const bf16x8*>(hr + ks * 16);
    f32x4 acc[4];
    #pragma unroll
    for (int cf = 0; cf < 4; ++cf) acc[cf] = (f32x4){0.f, 0.f, 0.f, 0.f};
    #pragma unroll
    for (int cf = 0; cf < 4; ++cf) {
        #pragma unroll
        for (int ks = 0; ks < 4; ++ks) {
            const bf16x8 wf = *reinterpret_cast<const bf16x8*>(w1p + cf * 1088 + ks * 16);
            acc[cf] = __builtin_amdgcn_mfma_f32_16x16x32_bf16(af[ks], wf, acc[cf], 0, 0, 0);
        }
    }
    #pragma unroll
    for (int cf = 0; cf < 4; ++cf) {
        #pragma unroll
        for (int jj = 0; jj < 4; ++jj) {
            float th = (acc[cf][jj] + b1v[cf]) * inv_scale;
            th = 1.0f - 2.0f / (__expf(2.0f * th) + 1.0f);   // tanh, inf-safe
            thw[(g * 4 + jj) * 72 + cf * 16 + c] = f2bf(th);
        }
    }
    f32x4 acc2 = (f32x4){0.f, 0.f, 0.f, 0.f};
    #pragma unroll
    for (int ks2 = 0; ks2 < 2; ++ks2) {
        bf16x8 pa = *reinterpret_cast<const bf16x8*>(&thw[c * 72 + ks2 * 32 + g * 8]);
        acc2 = __builtin_amdgcn_mfma_f32_16x16x32_bf16(pa, wf2[ks2], acc2, 0, 0, 0);
    }
    if (c < 8) {
        float4 o;
        o.x = acc2[0] + b2v; o.y = acc2[1] + b2v;
        o.z = acc2[2] + b2v; o.w = acc2[3] + b2v;
        *(float4*)&s2b[(size_t)c * L_ + tile * 64 + w * 16 + g * 4] = o;
    }
}

// ---------------- K1: R6 pipeline at 3 blocks/CU (52.2 KB LDS, persistent slots) ------
// 768 blocks = 64 batches x 12 slots; slot s handles tiles {s, s+12, ...} (<64):
// slots 0..3 do 6 tiles, 4..11 do 5. All waves of a block share the trip count
// (barriers uniform). Pipeline per tile: compute(cur) | pack(next->cur^1) |
// load(next2) | store(next) | lds_barrier. Loads always precede the stores that
// could alias their registers by a full iteration.
__global__ __launch_bounds__(256, 3)
void k1_mfma(const float* __restrict__ node, const float* __restrict__ neigh,
             const int* __restrict__ nnum, const float* __restrict__ W1,
             const float* __restrict__ b1, const float* __restrict__ W2,
             const float* __restrict__ b2, float* __restrict__ out)
{
    __shared__ __align__(16) unsigned w1lds[64 * 68];      // 17.0 KB
    __shared__ __align__(16) unsigned hlds[2][64 * 68];    // 34.8 KB (th tiles aliased)

    const int tid  = threadIdx.x;
    const int w    = tid >> 6;
    const int lane = tid & 63;
    const int c    = lane & 15;
    const int g    = lane >> 4;

    const int bb   = blockIdx.x / 12;
    const int slot = blockIdx.x - bb * 12;
    const int ntiles = (slot < 4) ? 6 : 5;

    const float* nbase = neigh + (size_t)bb * L_ * HID;
    float*       cbase = out + OFF_NEIGH + (size_t)bb * L_ * HID;
    float*       s2b   = out + OFF_A + (size_t)bb * HOPS * L_;

    // ---- prologue: tile(slot) loads in flight across all staging ----
    float4 va[8], vb[8];
    load_tile(va, nbase + (size_t)slot * 8192, tid);

    // node rows packed bf16 (loop-invariant: node row = global row % 64)
    uint2 npk[8];
    {
        const float* ndb = node + (size_t)bb * T_ * HID;
        const int arow0 = tid >> 5;
        const int acol  = (tid * 4) & 127;
        #pragma unroll
        for (int r = 0; r < 8; ++r) {
            float4 nv = *(const float4*)(ndb + (r * 8 + arow0) * HID + acol);
            npk[r].x = pkbf(nv.x, nv.y);
            npk[r].y = pkbf(nv.z, nv.w);
        }
    }
    // stage W1 -> LDS bf16
    {
        const int a = tid >> 2, qq = tid & 3;
        const float* src = W1 + a * HID + qq * 32;
        float x[32];
        #pragma unroll
        for (int i = 0; i < 8; ++i) *(float4*)&x[i * 4] = *(const float4*)(src + i * 4);
        unsigned* dst = &w1lds[a * 68 + qq * 16];
        #pragma unroll
        for (int i = 0; i < 16; ++i) dst[i] = pkbf(x[2 * i], x[2 * i + 1]);
    }
    // W2 B-fragments in registers
    bf16x8 wf2[2];
    #pragma unroll
    for (int ks2 = 0; ks2 < 2; ++ks2) {
        union { bf16x8 vv; unsigned u[4]; } t;
        #pragma unroll
        for (int i = 0; i < 4; ++i) {
            float lo = (c < 8) ? W2[c * 64 + ks2 * 32 + g * 8 + 2 * i]     : 0.f;
            float hi = (c < 8) ? W2[c * 64 + ks2 * 32 + g * 8 + 2 * i + 1] : 0.f;
            t.u[i] = pkbf(lo, hi);
        }
        wf2[ks2] = t.vv;
    }
    float b1v[4];
    #pragma unroll
    for (int cf = 0; cf < 4; ++cf) b1v[cf] = b1[cf * 16 + c];
    const float b2v = (c < 8) ? b2[c] : 0.f;
    const float inv_scale = rsqrtf((float)nnum[0]);

    // prologue pipeline fill: pack tile(slot), launch tile(slot+12), store tile(slot)
    pack_tile(va, npk, hlds[0], tid);                        // waits va only
    load_tile(vb, nbase + (size_t)(slot + 12) * 8192, tid);  // always exists (ntiles>=5)
    store_tile(va, cbase + (size_t)slot * 8192, tid);
    lds_barrier();

    // steady state, manually unrolled 6 steps (ntiles is 5 or 6, block-uniform)
#define STEP(I, VCUR, VNXT)                                                         \
    if ((I) < ntiles) {                                                             \
        compute_tile(hlds[(I) & 1], w1lds, wf2, b1v, b2v, inv_scale, s2b,           \
                     slot + 12 * (I), w, c, g);                                     \
        if ((I) + 1 < ntiles) {                                                     \
            pack_tile(VNXT, npk, hlds[((I) + 1) & 1], tid);                         \
            if ((I) + 2 < ntiles)                                                   \
                load_tile(VCUR, nbase + (size_t)(slot + 12 * ((I) + 2)) * 8192, tid); \
            store_tile(VNXT, cbase + (size_t)(slot + 12 * ((I) + 1)) * 8192, tid);  \
            lds_barrier();                                                          \
        }                                                                           \
    }
    STEP(0, va, vb)
    STEP(1, vb, va)
    STEP(2, va, vb)
    STEP(3, vb, va)
    STEP(4, va, vb)
    STEP(5, vb, va)
#undef STEP
}

// ---------------- reductions helpers ----------------
__device__ __forceinline__ float waveMax(float v) {
    #pragma unroll
    for (int o = 32; o > 0; o >>= 1) v = fmaxf(v, __shfl_xor(v, o));
    return v;
}
__device__ __forceinline__ float waveSum(float v) {
    #pragma unroll
    for (int o = 32; o > 0; o >>= 1) v += __shfl_xor(v, o);
    return v;
}

// ---------------- K2: per-(b,h) softmax stats + zero aat accumulators ----------------
__global__ __launch_bounds__(256)
void k2_stats(const float* __restrict__ out, float* __restrict__ stats, float* __restrict__ aat)
{
    const int bh = blockIdx.x;                         // 0..511
    const int tid = threadIdx.x;
    if (bh == 0) {
        for (int i = tid; i < B_ * 36; i += 256) aat[i] = 0.f;
    }
    const float* row = out + OFF_A + (size_t)bh * L_;
    __shared__ float red[8];
    float m = -3.4e38f;
    for (int i = tid; i < L_; i += 256) m = fmaxf(m, row[i]);
    m = waveMax(m);
    if ((tid & 63) == 0) red[tid >> 6] = m;
    __syncthreads();
    const float M = fmaxf(fmaxf(red[0], red[1]), fmaxf(red[2], red[3]));
    float s = 0.0f;
    for (int i = tid; i < L_; i += 256) s += __expf(row[i] - M);
    s = waveSum(s);
    if ((tid & 63) == 0) red[4 + (tid >> 6)] = s;
    __syncthreads();
    if (tid == 0) {
        stats[bh * 2]     = M;
        stats[bh * 2 + 1] = red[4] + red[5] + red[6] + red[7];
    }
}

// ---------------- K3: in-place A = softmax, BW, AAT upper-tri partials (atomic) -------
__global__ __launch_bounds__(256)
void k3_soft(float* __restrict__ out, const float* __restrict__ stats, float* __restrict__ aat)
{
    const int blk = blockIdx.x;        // 256 blocks, 4 per batch
    const int b   = blk >> 2;
    const int l0  = (blk & 3) << 10;   // 1024 l's each
    const int tid = threadIdx.x;
    float* A0 = out + OFF_A + (size_t)b * HOPS * L_;
    float* BW = out + (size_t)b * L_;
    float M[HOPS], R[HOPS];
    #pragma unroll
    for (int hh = 0; hh < HOPS; ++hh) {
        M[hh] = stats[(b * HOPS + hh) * 2];
        R[hh] = 1.0f / stats[(b * HOPS + hh) * 2 + 1];
    }
    float p[36];
    #pragma unroll
    for (int i = 0; i < 36; ++i) p[i] = 0.0f;
    for (int l = l0 + tid; l < l0 + 1024; l += 256) {
        float e[HOPS]; float srow = 0.0f;
        #pragma unroll
        for (int hh = 0; hh < HOPS; ++hh) {
            float v = __expf(A0[hh * L_ + l] - M[hh]) * R[hh];
            e[hh] = v; srow += v;
        }
        #pragma unroll
        for (int hh = 0; hh < HOPS; ++hh) A0[hh * L_ + l] = e[hh];
        BW[l] = srow;
        int i = 0;
        #pragma unroll
        for (int hh = 0; hh < HOPS; ++hh) {
            #pragma unroll
            for (int gg = hh; gg < HOPS; ++gg) { p[i] = fmaf(e[hh], e[gg], p[i]); ++i; }
        }
    }
    #pragma unroll
    for (int i = 0; i < 36; ++i) p[i] = waveSum(p[i]);
    __shared__ float red[4][36];
    const int wv = tid >> 6, ln = tid & 63;
    if (ln == 0) {
        #pragma unroll
        for (int i = 0; i < 36; ++i) red[wv][i] = p[i];
    }
    __syncthreads();
    if (tid < 36) {
        float s = red[0][tid] + red[1][tid] + red[2][tid] + red[3][tid];
        atomicAdd(&aat[b * 36 + tid], s);
    }
}

// ---------------- K4: penal = sum_b sum((AAT_b - I)^2), off-diag counted twice --------
__global__ __launch_bounds__(256)
void k4_penal(const float* __restrict__ aat, float* __restrict__ out)
{
    const int tid = threadIdx.x;
    float s = 0.0f;
    for (int i = tid; i < B_ * 36; i += 256) {
        int r = i % 36;
        bool dg = (r == 0) | (r == 8) | (r == 15) | (r == 21) |
                  (r == 26) | (r == 30) | (r == 33) | (r == 35);
        float d = aat[i] - (dg ? 1.0f : 0.0f);
        float qd = d * d;
        s += dg ? qd : 2.0f * qd;
    }
    s = waveSum(s);
    __shared__ float red[4];
    if ((tid & 63) == 0) red[tid >> 6] = s;
    __syncthreads();
    if (tid == 0) out[OFF_PENAL] = red[0] + red[1] + red[2] + red[3];
}

extern "C" void kernel_launch(void* const* d_in, const int* in_sizes, int n_in,
                              void* d_out, int out_size, void* d_ws, size_t ws_size,
                              hipStream_t stream) {
    const float* node  = (const float*)d_in[0];
    const float* neigh = (const float*)d_in[1];
    const int*   nnum  = (const int*)d_in[2];   // low 32 bits of elem 0 (LE, value in [1,64))
    const float* W1    = (const float*)d_in[3];
    const float* b1    = (const float*)d_in[4];
    const float* W2    = (const float*)d_in[5];
    const float* b2    = (const float*)d_in[6];
    float* out   = (float*)d_out;
    float* stats = (float*)d_ws;          // 1024 floats
    float* aat   = stats + 1024;          // 64*36 floats (upper-tri, accumulated)

    k1_mfma <<<768, 256, 0, stream>>>(node, neigh, nnum, W1, b1, W2, b2, out);
    k2_stats<<<B_ * HOPS, 256, 0, stream>>>(out, stats, aat);
    k3_soft <<<256, 256, 0, stream>>>(out, stats, aat);
    k4_penal<<<1, 256, 0, stream>>>(aat, out);
}